// Round 1
// baseline (228.775 us; speedup 1.0000x reference)
//
#include <hip/hip_runtime.h>

#define NB 256
#define NT 1024
#define NL 64

// --- lane broadcast helpers (SGPR results) ---
__device__ __forceinline__ float rl_f(float v, int lane) {
  return __builtin_bit_cast(float, __builtin_amdgcn_readlane(__builtin_bit_cast(int, v), lane));
}
__device__ __forceinline__ float rfl_f(float v) {
  return __builtin_bit_cast(float, __builtin_amdgcn_readfirstlane(__builtin_bit_cast(int, v)));
}

// One CRF step in p-space: p_new[cur] = (sum_prev p[prev]*R[prev->cur]) * E[cur] * 2^-e
// e = exponent of lane0's value (uniform power-of-2 renorm, exact; tracked in e2sum).
__device__ __forceinline__ void crf_step(float& p, int& e2sum, const float* __restrict__ R, float E) {
  float s0 = 0.f, s1 = 0.f, s2 = 0.f, s3 = 0.f;
#pragma unroll
  for (int j = 0; j < NL; j += 4) {
    float p0 = rl_f(p, j + 0);
    float p1 = rl_f(p, j + 1);
    float p2 = rl_f(p, j + 2);
    float p3 = rl_f(p, j + 3);
    s0 = __builtin_fmaf(p0, R[j + 0], s0);
    s1 = __builtin_fmaf(p1, R[j + 1], s1);
    s2 = __builtin_fmaf(p2, R[j + 2], s2);
    s3 = __builtin_fmaf(p3, R[j + 3], s3);
  }
  float u = ((s0 + s1) + (s2 + s3)) * E;
  int ub = __builtin_amdgcn_readfirstlane(__builtin_bit_cast(int, u));
  int eb = (ub >> 23) & 0xff;                                // exponent field of u[0] (u>0 always)
  float K = __builtin_bit_cast(float, (254 - eb) << 23);     // 2^-(eb-127)
  p = u * K;
  e2sum += eb - 127;
}

// Forward (blocks 0..255) and backward (blocks 256..511) recurrences.
// Each block = 1 wave = 1 (batch, direction). Meet at t=512:
//   alpha_512 includes emits 0..512, beta_512 includes emits 513..1023.
__global__ __launch_bounds__(64) void fb_kernel(const float* __restrict__ scores,
                                                const float* __restrict__ start,
                                                const float* __restrict__ Tm,
                                                const float* __restrict__ endv,
                                                float* __restrict__ wsA,
                                                float* __restrict__ wsB) {
  const int lane = threadIdx.x;
  const int bb = blockIdx.x;
  const bool bwd = bb >= NB;
  const int b = bwd ? bb - NB : bb;
  const float* sc = scores + (size_t)b * NT * NL;
  const float LN2 = 0.69314718055994530942f;

  float R[NL];  // expT row (fwd: R[prev]=exp(T[lane,prev])) / col (bwd: R[cur]=exp(T[cur,lane]))
  if (!bwd) {
#pragma unroll
    for (int j = 0; j < NL; j++) R[j] = __expf(Tm[lane * NL + j]);

    float a0 = start[lane] + sc[lane];  // alpha_0
    float m0 = rfl_f(a0);
    float p = __expf(a0 - m0);
    int e2 = 0;

    float buf[4];
#pragma unroll
    for (int k = 0; k < 4; k++) buf[k] = sc[(1 + k) * NL + lane];

    for (int i = 0; i < 128; i++) {  // 512 steps: t = 1..512
      float nb4[4];
      int tb = 5 + 4 * i;  // prefetch next block (max t=516 < 1024, always valid)
#pragma unroll
      for (int k = 0; k < 4; k++) nb4[k] = sc[(tb + k) * NL + lane];
      float Ev[4];
#pragma unroll
      for (int k = 0; k < 4; k++) Ev[k] = __expf(buf[k]);  // off critical chain
#pragma unroll
      for (int k = 0; k < 4; k++) crf_step(p, e2, R, Ev[k]);
#pragma unroll
      for (int k = 0; k < 4; k++) buf[k] = nb4[k];
    }
    wsA[b * NL + lane] = m0 + (float)e2 * LN2 + __logf(p);  // alpha_512
  } else {
#pragma unroll
    for (int j = 0; j < NL; j++) R[j] = __expf(Tm[j * NL + lane]);

    float a0 = endv[lane] + sc[(NT - 1) * NL + lane];  // q_1023 = exp(end + emit_1023)
    float m0 = rfl_f(a0);
    float p = __expf(a0 - m0);
    int e2 = 0;

    float buf[4];
#pragma unroll
    for (int k = 0; k < 4; k++) buf[k] = sc[(1022 - k) * NL + lane];

    for (int i = 0; i < 127; i++) {  // 508 full-E steps: te = 1022..515
      float nb4[4];
      int tb = 1018 - 4 * i;  // prefetch next block (min te=511 >= 0, always valid)
#pragma unroll
      for (int k = 0; k < 4; k++) nb4[k] = sc[(tb - k) * NL + lane];
      float Ev[4];
#pragma unroll
      for (int k = 0; k < 4; k++) Ev[k] = __expf(buf[k]);
#pragma unroll
      for (int k = 0; k < 4; k++) crf_step(p, e2, R, Ev[k]);
#pragma unroll
      for (int k = 0; k < 4; k++) buf[k] = nb4[k];
    }
    // remaining full-E steps: te = 514, 513
    crf_step(p, e2, R, __expf(sc[514 * NL + lane]));
    crf_step(p, e2, R, __expf(sc[513 * NL + lane]));
    // final matvec-only step (E=1) -> beta_512 (emit_512 belongs to alpha side)
    crf_step(p, e2, R, 1.0f);
    wsB[b * NL + lane] = m0 + (float)e2 * LN2 + __logf(p);  // beta_512
  }
}

// Gold-path score + combine alpha/beta into per-batch loss.
__global__ __launch_bounds__(256) void gold_kernel(const float* __restrict__ scores,
                                                   const int* __restrict__ targets,
                                                   const float* __restrict__ start,
                                                   const float* __restrict__ Tm,
                                                   const float* __restrict__ endv,
                                                   const float* __restrict__ wsA,
                                                   const float* __restrict__ wsB,
                                                   float* __restrict__ wsLoss) {
  const int b = blockIdx.x, tid = threadIdx.x;
  const int* tg = targets + b * NT;
  const float* sc = scores + (size_t)b * NT * NL;

  float acc = 0.f;
  for (int t = tid; t < NT; t += 256) {
    int c = tg[t];
    acc += sc[t * NL + c];
    if (t > 0) acc += Tm[c * NL + tg[t - 1]];  // T_mat[cur, prev]
  }
#pragma unroll
  for (int off = 32; off > 0; off >>= 1) acc += __shfl_xor(acc, off, 64);
  __shared__ float red[4];
  if ((tid & 63) == 0) red[tid >> 6] = acc;
  __syncthreads();

  if (tid < 64) {
    float gold = red[0] + red[1] + red[2] + red[3] + start[tg[0]] + endv[tg[NT - 1]];
    float v = wsA[b * NL + tid] + wsB[b * NL + tid];
    float m = v;
#pragma unroll
    for (int off = 32; off > 0; off >>= 1) m = fmaxf(m, __shfl_xor(m, off, 64));
    float e = __expf(v - m);
#pragma unroll
    for (int off = 32; off > 0; off >>= 1) e += __shfl_xor(e, off, 64);
    if (tid == 0) wsLoss[b] = (m + __logf(e)) - gold;
  }
}

__global__ __launch_bounds__(256) void final_kernel(const float* __restrict__ wsLoss,
                                                    float* __restrict__ out) {
  int tid = threadIdx.x;
  float v = wsLoss[tid];
#pragma unroll
  for (int off = 32; off > 0; off >>= 1) v += __shfl_xor(v, off, 64);
  __shared__ float red[4];
  if ((tid & 63) == 0) red[tid >> 6] = v;
  __syncthreads();
  if (tid == 0) out[0] = (red[0] + red[1] + red[2] + red[3]) * (1.0f / NB);
}

extern "C" void kernel_launch(void* const* d_in, const int* in_sizes, int n_in,
                              void* d_out, int out_size, void* d_ws, size_t ws_size,
                              hipStream_t stream) {
  const float* scores = (const float*)d_in[0];
  const int* targets = (const int*)d_in[1];
  const float* start = (const float*)d_in[2];
  const float* Tm = (const float*)d_in[3];
  const float* endv = (const float*)d_in[4];
  float* out = (float*)d_out;

  float* wsA = (float*)d_ws;            // [NB*NL] alpha_512
  float* wsB = wsA + NB * NL;           // [NB*NL] beta_512
  float* wsLoss = wsB + NB * NL;        // [NB] per-batch loss

  fb_kernel<<<2 * NB, 64, 0, stream>>>(scores, start, Tm, endv, wsA, wsB);
  gold_kernel<<<NB, 256, 0, stream>>>(scores, targets, start, Tm, endv, wsA, wsB, wsLoss);
  final_kernel<<<1, 256, 0, stream>>>(wsLoss, out);
}

// Round 3
// 181.601 us; speedup vs baseline: 1.2598x; 1.2598x over previous
//
#include <hip/hip_runtime.h>

#define NB 256
#define NT 1024
#define NL 64

typedef __fp16 h2v __attribute__((ext_vector_type(2)));

__device__ __forceinline__ float rfl_f(float v) {
  return __builtin_bit_cast(float, __builtin_amdgcn_readfirstlane(__builtin_bit_cast(int, v)));
}

// partner = value from lane^1, via DPP quad_perm [1,0,3,2] (VALU, no LDS pipe)
__device__ __forceinline__ float dpp_xor1(float v) {
  int i = __builtin_bit_cast(int, v);
  int r = __builtin_amdgcn_update_dpp(i, i, 0xB1, 0xF, 0xF, false);
  return __builtin_bit_cast(float, r);
}

// 8 readlanes batched ahead of their 8 dot2s: buries the VALU->SGPR->VALU hazard.
#define CRF_DOT8(K0)                                                          \
  do {                                                                        \
    int b0 = __builtin_amdgcn_readlane(pki, 2 * (K0 + 0));                    \
    int b1 = __builtin_amdgcn_readlane(pki, 2 * (K0 + 1));                    \
    int b2 = __builtin_amdgcn_readlane(pki, 2 * (K0 + 2));                    \
    int b3 = __builtin_amdgcn_readlane(pki, 2 * (K0 + 3));                    \
    int b4 = __builtin_amdgcn_readlane(pki, 2 * (K0 + 4));                    \
    int b5 = __builtin_amdgcn_readlane(pki, 2 * (K0 + 5));                    \
    int b6 = __builtin_amdgcn_readlane(pki, 2 * (K0 + 6));                    \
    int b7 = __builtin_amdgcn_readlane(pki, 2 * (K0 + 7));                    \
    s0 = __builtin_amdgcn_fdot2(__builtin_bit_cast(h2v, b0), Rh[K0 + 0], s0, false); \
    s1 = __builtin_amdgcn_fdot2(__builtin_bit_cast(h2v, b1), Rh[K0 + 1], s1, false); \
    s2 = __builtin_amdgcn_fdot2(__builtin_bit_cast(h2v, b2), Rh[K0 + 2], s2, false); \
    s3 = __builtin_amdgcn_fdot2(__builtin_bit_cast(h2v, b3), Rh[K0 + 3], s3, false); \
    s0 = __builtin_amdgcn_fdot2(__builtin_bit_cast(h2v, b4), Rh[K0 + 4], s0, false); \
    s1 = __builtin_amdgcn_fdot2(__builtin_bit_cast(h2v, b5), Rh[K0 + 5], s1, false); \
    s2 = __builtin_amdgcn_fdot2(__builtin_bit_cast(h2v, b6), Rh[K0 + 6], s2, false); \
    s3 = __builtin_amdgcn_fdot2(__builtin_bit_cast(h2v, b7), Rh[K0 + 7], s3, false); \
  } while (0)

// One CRF step: new_p[cur] = (sum_prev p[prev]*R[prev->cur]) * E[cur], renormed
// by 2^-(lane0_exponent - 2) so the state stays in f16-safe range [~2^-2 .. ~2e4].
#define CRF_STEP(EF)                                                          \
  do {                                                                        \
    float pn = dpp_xor1(p);                                                   \
    h2v pk = __builtin_amdgcn_cvt_pkrtz(p, pn);                               \
    int pki = __builtin_bit_cast(int, pk);                                    \
    float s0 = 0.f, s1 = 0.f, s2 = 0.f, s3 = 0.f;                             \
    CRF_DOT8(0);                                                              \
    CRF_DOT8(8);                                                              \
    CRF_DOT8(16);                                                             \
    CRF_DOT8(24);                                                             \
    float u = ((s0 + s1) + (s2 + s3)) * (EF);                                 \
    int ub = __builtin_amdgcn_readfirstlane(__builtin_bit_cast(int, u));      \
    int eb = (ub >> 23) & 0xff;                                               \
    p = u * __builtin_bit_cast(float, (252 - eb) << 23);                      \
    e2 += eb - 125;                                                           \
  } while (0)

// Blocks 0..255: forward chains. 256..511: backward chains. 512..767: gold path
// (latency hides under the fb waves co-resident on the same CUs).
__global__ __launch_bounds__(64) void fb_kernel(const float* __restrict__ scores,
                                                const int* __restrict__ targets,
                                                const float* __restrict__ start,
                                                const float* __restrict__ Tm,
                                                const float* __restrict__ endv,
                                                float* __restrict__ wsA,
                                                float* __restrict__ wsB,
                                                float* __restrict__ wsG) {
  const int lane = threadIdx.x;
  const int bb = blockIdx.x;

  if (bb >= 2 * NB) {  // ---- gold path: one wave per batch ----
    const int b = bb - 2 * NB;
    const int* tg = targets + b * NT;
    const float* sc = scores + (size_t)b * NT * NL;
    float acc = 0.f;
    for (int t = lane; t < NT; t += 64) {
      int c = tg[t];
      acc += sc[t * NL + c];
      if (t > 0) acc += Tm[c * NL + tg[t - 1]];  // T_mat[cur, prev]
    }
#pragma unroll
    for (int off = 32; off > 0; off >>= 1) acc += __shfl_xor(acc, off, 64);
    if (lane == 0) wsG[b] = acc + start[tg[0]] + endv[tg[NT - 1]];
    return;
  }

  const bool bwd = bb >= NB;
  const int b = bwd ? bb - NB : bb;
  const float* sc = scores + (size_t)b * NT * NL;
  const float LN2 = 0.69314718055994530942f;

  // f16x2 transition table: fwd Rh[k] = (exp(T[lane][2k]), exp(T[lane][2k+1]))
  //                         bwd Rh[k] = (exp(T[2k][lane]), exp(T[2k+1][lane]))
  const float* Tb = bwd ? (Tm + lane) : (Tm + lane * NL);
  const int str = bwd ? NL : 1;
  h2v Rh[32];
#pragma unroll
  for (int k = 0; k < 32; k++)
    Rh[k] = __builtin_amdgcn_cvt_pkrtz(__expf(Tb[(2 * k) * str]),
                                       __expf(Tb[(2 * k + 1) * str]));

  if (!bwd) {
    float a0 = start[lane] + sc[lane];  // alpha_0
    float m0 = rfl_f(a0);
    float p = __expf(a0 - m0) * 0.25f;
    int e2 = 2;

    float buf[4];
#pragma unroll
    for (int k = 0; k < 4; k++) buf[k] = sc[(1 + k) * NL + lane];

    for (int i = 0; i < 128; i++) {  // 512 steps: t = 1..512
      float nb4[4];
      int tb = 5 + 4 * i;  // prefetch (max t=516 < 1024)
#pragma unroll
      for (int k = 0; k < 4; k++) nb4[k] = sc[(tb + k) * NL + lane];
      float Ev[4];
#pragma unroll
      for (int k = 0; k < 4; k++) Ev[k] = __expf(buf[k]);  // off critical chain
      CRF_STEP(Ev[0]);
      CRF_STEP(Ev[1]);
      CRF_STEP(Ev[2]);
      CRF_STEP(Ev[3]);
#pragma unroll
      for (int k = 0; k < 4; k++) buf[k] = nb4[k];
    }
    wsA[lane * NB + b] = m0 + (float)e2 * LN2 + __logf(p);  // alpha_512 (transposed)
  } else {
    float a0 = endv[lane] + sc[(NT - 1) * NL + lane];
    float m0 = rfl_f(a0);
    float p = __expf(a0 - m0) * 0.25f;
    int e2 = 2;

    float buf[4];
#pragma unroll
    for (int k = 0; k < 4; k++) buf[k] = sc[(1022 - k) * NL + lane];

    for (int i = 0; i < 127; i++) {  // 508 steps: te = 1022..515
      float nb4[4];
      int tb = 1018 - 4 * i;  // prefetch (min 511 >= 0)
#pragma unroll
      for (int k = 0; k < 4; k++) nb4[k] = sc[(tb - k) * NL + lane];
      float Ev[4];
#pragma unroll
      for (int k = 0; k < 4; k++) Ev[k] = __expf(buf[k]);
      CRF_STEP(Ev[0]);
      CRF_STEP(Ev[1]);
      CRF_STEP(Ev[2]);
      CRF_STEP(Ev[3]);
#pragma unroll
      for (int k = 0; k < 4; k++) buf[k] = nb4[k];
    }
    CRF_STEP(__expf(sc[514 * NL + lane]));
    CRF_STEP(__expf(sc[513 * NL + lane]));
    CRF_STEP(1.0f);  // final matvec-only step -> beta_512
    wsB[lane * NB + b] = m0 + (float)e2 * LN2 + __logf(p);  // beta_512 (transposed)
  }
}

// thread b handles batch b: lse over 64 states (coalesced via transposed ws layout),
// subtract gold, block-reduce mean.
__global__ __launch_bounds__(256) void combine_kernel(const float* __restrict__ wsA,
                                                      const float* __restrict__ wsB,
                                                      const float* __restrict__ wsG,
                                                      float* __restrict__ out) {
  const int b = threadIdx.x;
  float m = -INFINITY;
#pragma unroll
  for (int j = 0; j < NL; j++) m = fmaxf(m, wsA[j * NB + b] + wsB[j * NB + b]);
  float s = 0.f;
#pragma unroll
  for (int j = 0; j < NL; j++) s += __expf(wsA[j * NB + b] + wsB[j * NB + b] - m);
  float loss = (m + __logf(s)) - wsG[b];
#pragma unroll
  for (int off = 32; off > 0; off >>= 1) loss += __shfl_xor(loss, off, 64);
  __shared__ float red[4];
  if ((b & 63) == 0) red[b >> 6] = loss;
  __syncthreads();
  if (b == 0) out[0] = (red[0] + red[1] + red[2] + red[3]) * (1.0f / NB);
}

extern "C" void kernel_launch(void* const* d_in, const int* in_sizes, int n_in,
                              void* d_out, int out_size, void* d_ws, size_t ws_size,
                              hipStream_t stream) {
  const float* scores = (const float*)d_in[0];
  const int* targets = (const int*)d_in[1];
  const float* start = (const float*)d_in[2];
  const float* Tm = (const float*)d_in[3];
  const float* endv = (const float*)d_in[4];
  float* out = (float*)d_out;

  float* wsA = (float*)d_ws;       // [NL*NB] alpha_512, transposed [state][batch]
  float* wsB = wsA + NB * NL;      // [NL*NB] beta_512, transposed
  float* wsG = wsB + NB * NL;      // [NB] gold path scores

  fb_kernel<<<3 * NB, 64, 0, stream>>>(scores, targets, start, Tm, endv, wsA, wsB, wsG);
  combine_kernel<<<1, 256, 0, stream>>>(wsA, wsB, wsG, out);
}

// Round 4
// 178.289 us; speedup vs baseline: 1.2832x; 1.0186x over previous
//
#include <hip/hip_runtime.h>

#define NB 256
#define NT 1024
#define NL 64

typedef __fp16 h2v __attribute__((ext_vector_type(2)));

__device__ __forceinline__ float rfl_f(float v) {
  return __builtin_bit_cast(float, __builtin_amdgcn_readfirstlane(__builtin_bit_cast(int, v)));
}

// partner = value from lane^1, via DPP quad_perm [1,0,3,2] (VALU, no LDS pipe)
__device__ __forceinline__ float dpp_xor1(float v) {
  int i = __builtin_bit_cast(int, v);
  int r = __builtin_amdgcn_update_dpp(i, i, 0xB1, 0xF, 0xF, false);
  return __builtin_bit_cast(float, r);
}

#define DOT4(P, B)                                                            \
  s0 = __builtin_amdgcn_fdot2(__builtin_bit_cast(h2v, (P).x), Rh[(B) + 0], s0, false); \
  s1 = __builtin_amdgcn_fdot2(__builtin_bit_cast(h2v, (P).y), Rh[(B) + 1], s1, false); \
  s2 = __builtin_amdgcn_fdot2(__builtin_bit_cast(h2v, (P).z), Rh[(B) + 2], s2, false); \
  s3 = __builtin_amdgcn_fdot2(__builtin_bit_cast(h2v, (P).w), Rh[(B) + 3], s3, false);

// One CRF step, LDS-broadcast version.
//  - pack (w, w_partner) -> f16x2, write 1 b32 to LDS (even lanes' pairs land
//    compacted in words 0..31; odd lanes write harmlessly to words 32..63)
//  - 8 uniform-address ds_read_b128 broadcast all 32 pairs to every lane
//  - renorm scale K = 2^-(e5-15)-12 extracted from pair0's f16 exponent:
//    uniform across lanes, pure VALU, folded into the emit factor (1 mul).
//  - w_new[lane] = (sum_prev w[prev] * R[prev][lane]) * E[lane] * K
#define CRF_STEP(EF)                                                          \
  do {                                                                        \
    float wn = dpp_xor1(w);                                                   \
    h2v pk = __builtin_amdgcn_cvt_pkrtz(w, wn);                               \
    lb[wslot] = __builtin_bit_cast(int, pk);                                  \
    int4 P0 = lbv[0], P1 = lbv[1], P2 = lbv[2], P3 = lbv[3];                  \
    int4 P4 = lbv[4], P5 = lbv[5], P6 = lbv[6], P7 = lbv[7];                  \
    int e5 = (P0.x >> 10) & 0x1f;                                             \
    float K = __builtin_bit_cast(float, (130 - e5) << 23);                    \
    float KE = K * (EF);                                                      \
    e2 += e5 - 3;                                                             \
    float s0 = 0.f, s1 = 0.f, s2 = 0.f, s3 = 0.f;                             \
    DOT4(P0, 0); DOT4(P1, 4); DOT4(P2, 8); DOT4(P3, 12);                      \
    DOT4(P4, 16); DOT4(P5, 20); DOT4(P6, 24); DOT4(P7, 28);                   \
    w = ((s0 + s1) + (s2 + s3)) * KE;                                         \
  } while (0)

// Blocks 0..255: forward chains. 256..511: backward chains. 512..767: gold path
// (hides under the fb waves co-resident on the same CUs).
__global__ __launch_bounds__(64) void fb_kernel(const float* __restrict__ scores,
                                                const int* __restrict__ targets,
                                                const float* __restrict__ start,
                                                const float* __restrict__ Tm,
                                                const float* __restrict__ endv,
                                                float* __restrict__ wsA,
                                                float* __restrict__ wsB,
                                                float* __restrict__ wsG) {
  const int lane = threadIdx.x;
  const int bb = blockIdx.x;

  if (bb >= 2 * NB) {  // ---- gold path: one wave per batch ----
    const int b = bb - 2 * NB;
    const int* tg = targets + b * NT;
    const float* sc = scores + (size_t)b * NT * NL;
    float acc = 0.f;
    for (int t = lane; t < NT; t += 64) {
      int c = tg[t];
      acc += sc[t * NL + c];
      if (t > 0) acc += Tm[c * NL + tg[t - 1]];  // T_mat[cur, prev]
    }
#pragma unroll
    for (int off = 32; off > 0; off >>= 1) acc += __shfl_xor(acc, off, 64);
    if (lane == 0) wsG[b] = acc + start[tg[0]] + endv[tg[NT - 1]];
    return;
  }

  __shared__ int4 lbv_s[16];        // 64 words: 0..31 = consumed pairs, 32..63 = scratch
  int* lb = (int*)lbv_s;
  const int4* lbv = lbv_s;
  const int wslot = (lane & 1) * 32 + (lane >> 1);  // 2 lanes/bank -> conflict-free

  const bool bwd = bb >= NB;
  const int b = bwd ? bb - NB : bb;
  const float* sc = scores + (size_t)b * NT * NL;
  const float LN2 = 0.69314718055994530942f;

  // f16x2 transition table: fwd Rh[k] = (exp(T[lane][2k]), exp(T[lane][2k+1]))
  //                         bwd Rh[k] = (exp(T[2k][lane]), exp(T[2k+1][lane]))
  const float* Tb = bwd ? (Tm + lane) : (Tm + lane * NL);
  const int str = bwd ? NL : 1;
  h2v Rh[32];
#pragma unroll
  for (int k = 0; k < 32; k++)
    Rh[k] = __builtin_amdgcn_cvt_pkrtz(__expf(Tb[(2 * k) * str]),
                                       __expf(Tb[(2 * k + 1) * str]));

  if (!bwd) {
    float a0 = start[lane] + sc[lane];  // alpha_0
    float m0 = rfl_f(a0);
    float w = __expf(a0 - m0) * 16.f;   // keep w_0 in f16-normal range
    int e2 = -4;

    float buf[4];
#pragma unroll
    for (int k = 0; k < 4; k++) buf[k] = sc[(1 + k) * NL + lane];

    for (int i = 0; i < 128; i++) {  // 512 steps: t = 1..512
      float nb4[4];
      int tb = 5 + 4 * i;  // prefetch (max t=516 < 1024)
#pragma unroll
      for (int k = 0; k < 4; k++) nb4[k] = sc[(tb + k) * NL + lane];
      float Ev[4];
#pragma unroll
      for (int k = 0; k < 4; k++) Ev[k] = __expf(buf[k]);  // off critical chain
      CRF_STEP(Ev[0]);
      CRF_STEP(Ev[1]);
      CRF_STEP(Ev[2]);
      CRF_STEP(Ev[3]);
#pragma unroll
      for (int k = 0; k < 4; k++) buf[k] = nb4[k];
    }
    wsA[lane * NB + b] = m0 + (float)e2 * LN2 + __logf(w);  // alpha_512 (transposed)
  } else {
    float a0 = endv[lane] + sc[(NT - 1) * NL + lane];
    float m0 = rfl_f(a0);
    float w = __expf(a0 - m0) * 16.f;
    int e2 = -4;

    float buf[4];
#pragma unroll
    for (int k = 0; k < 4; k++) buf[k] = sc[(1022 - k) * NL + lane];

    for (int i = 0; i < 127; i++) {  // 508 steps: te = 1022..515
      float nb4[4];
      int tb = 1018 - 4 * i;  // prefetch (min 511 >= 0)
#pragma unroll
      for (int k = 0; k < 4; k++) nb4[k] = sc[(tb - k) * NL + lane];
      float Ev[4];
#pragma unroll
      for (int k = 0; k < 4; k++) Ev[k] = __expf(buf[k]);
      CRF_STEP(Ev[0]);
      CRF_STEP(Ev[1]);
      CRF_STEP(Ev[2]);
      CRF_STEP(Ev[3]);
#pragma unroll
      for (int k = 0; k < 4; k++) buf[k] = nb4[k];
    }
    CRF_STEP(__expf(sc[514 * NL + lane]));
    CRF_STEP(__expf(sc[513 * NL + lane]));
    CRF_STEP(1.0f);  // final matvec-only step -> beta_512
    wsB[lane * NB + b] = m0 + (float)e2 * LN2 + __logf(w);  // beta_512 (transposed)
  }
}

// thread b handles batch b: lse over 64 states (coalesced via transposed ws layout),
// subtract gold, block-reduce mean.
__global__ __launch_bounds__(256) void combine_kernel(const float* __restrict__ wsA,
                                                      const float* __restrict__ wsB,
                                                      const float* __restrict__ wsG,
                                                      float* __restrict__ out) {
  const int b = threadIdx.x;
  float m = -INFINITY;
#pragma unroll
  for (int j = 0; j < NL; j++) m = fmaxf(m, wsA[j * NB + b] + wsB[j * NB + b]);
  float s = 0.f;
#pragma unroll
  for (int j = 0; j < NL; j++) s += __expf(wsA[j * NB + b] + wsB[j * NB + b] - m);
  float loss = (m + __logf(s)) - wsG[b];
#pragma unroll
  for (int off = 32; off > 0; off >>= 1) loss += __shfl_xor(loss, off, 64);
  __shared__ float red[4];
  if ((b & 63) == 0) red[b >> 6] = loss;
  __syncthreads();
  if (b == 0) out[0] = (red[0] + red[1] + red[2] + red[3]) * (1.0f / NB);
}

extern "C" void kernel_launch(void* const* d_in, const int* in_sizes, int n_in,
                              void* d_out, int out_size, void* d_ws, size_t ws_size,
                              hipStream_t stream) {
  const float* scores = (const float*)d_in[0];
  const int* targets = (const int*)d_in[1];
  const float* start = (const float*)d_in[2];
  const float* Tm = (const float*)d_in[3];
  const float* endv = (const float*)d_in[4];
  float* out = (float*)d_out;

  float* wsA = (float*)d_ws;       // [NL*NB] alpha_512, transposed [state][batch]
  float* wsB = wsA + NB * NL;      // [NL*NB] beta_512, transposed
  float* wsG = wsB + NB * NL;      // [NB] gold path scores

  fb_kernel<<<3 * NB, 64, 0, stream>>>(scores, targets, start, Tm, endv, wsA, wsB, wsG);
  combine_kernel<<<1, 256, 0, stream>>>(wsA, wsB, wsG, out);
}